// Round 9
// baseline (1073.081 us; speedup 1.0000x reference)
//
#include <hip/hip_runtime.h>
#include <cstdint>

#define NN 50000
#define NE 600000
#define NGR 256
#define HD 128
#define HD2 64            // bf16x2 packed words per row
#define NGRP 12500        // NN/4 node-quads
#define BN_EPS 1e-5f

// ---- bf16 pack/unpack (bit ops; values are normal floats, no inf/nan) ----
static __device__ __forceinline__ unsigned f2bf(float f) {
  unsigned u = __float_as_uint(f);
  return (u + 0x7FFFu + ((u >> 16) & 1u)) >> 16;   // round-to-nearest-even
}
static __device__ __forceinline__ float bf_lo(unsigned v) {
  return __uint_as_float(v << 16);
}
static __device__ __forceinline__ float bf_hi(unsigned v) {
  return __uint_as_float(v & 0xFFFF0000u);
}

// ---------------- zero scratch accumulators ----------------
__global__ void k_zero(float4* __restrict__ p, int n4) {
  int i = blockIdx.x * blockDim.x + threadIdx.x;
  if (i < n4) p[i] = make_float4(0.f, 0.f, 0.f, 0.f);
}

// ---------------- in-degree count ----------------
__global__ void k_count(const int* __restrict__ dst, int* __restrict__ cnt) {
  int i = blockIdx.x * blockDim.x + threadIdx.x;
  if (i < NE) atomicAdd(&cnt[dst[i]], 1);
}

// ---------------- CSR row-ptr scan (3 phases) ----------------
__global__ __launch_bounds__(1024) void k_scan1(const int* __restrict__ cnt,
                                                int* __restrict__ rowptr,
                                                int* __restrict__ aux,
                                                float* __restrict__ dis) {
  __shared__ int sd[1024];
  int tid = threadIdx.x;
  int i = blockIdx.x * 1024 + tid;
  int v = (i < NN) ? cnt[i] : 0;
  if (i < NN) dis[i] = 1.0f / sqrtf((float)v + 1.0f);
  sd[tid] = v;
  __syncthreads();
  for (int off = 1; off < 1024; off <<= 1) {
    int t = (tid >= off) ? sd[tid - off] : 0;
    __syncthreads();
    sd[tid] += t;
    __syncthreads();
  }
  if (i < NN) rowptr[i + 1] = sd[tid];
  if (tid == 1023) aux[blockIdx.x] = sd[1023];
}

__global__ void k_scan2(const int* __restrict__ aux, int* __restrict__ auxsc, int nchunks) {
  if (threadIdx.x == 0 && blockIdx.x == 0) {
    int run = 0;
    for (int c = 0; c < nchunks; ++c) { auxsc[c] = run; run += aux[c]; }
  }
}

__global__ void k_scan3(int* __restrict__ rowptr, const int* __restrict__ auxsc) {
  int i = blockIdx.x * blockDim.x + threadIdx.x;
  if (i < NN) rowptr[i + 1] += auxsc[i >> 10];
  if (i == 0) rowptr[0] = 0;
}

__global__ void k_fill(const int* __restrict__ src, const int* __restrict__ dst,
                       const int* __restrict__ rowptr, int* __restrict__ fillp,
                       int* __restrict__ colidx) {
  int i = blockIdx.x * blockDim.x + threadIdx.x;
  if (i < NE) {
    int d = dst[i];
    int p = rowptr[d] + atomicAdd(&fillp[d], 1);
    colidx[p] = src[i];
  }
}

// ---------------- GEMM: HS(bf16x2) = dis * (act(X) @ W) ----------------
template<bool BN>
__global__ __launch_bounds__(256) void k_gemm(
    const float* __restrict__ X, const float* __restrict__ W,
    const float* __restrict__ scale, const float* __restrict__ shift,
    const float* __restrict__ dis, unsigned* __restrict__ HS) {
  __shared__ float xt[64][36];    // stride 36: av reads land banks {k,k+16} -> 2-way alias (free)
  __shared__ float wt[32][132];   // stride 132: 16 float2 addrs cover all 32 banks -> conflict-free
  int tid = threadIdx.x;
  int tc = tid & 15;
  int tr = tid >> 4;
  int row0 = blockIdx.x * 64;
  int r0 = tr * 4;
  float acc[4][8];
#pragma unroll
  for (int i = 0; i < 4; ++i)
#pragma unroll
    for (int j = 0; j < 8; ++j) acc[i][j] = 0.f;

  int lr = tid >> 2;          // 0..63  (x-tile row)
  int lk = (tid & 3) * 8;     // 0,8,16,24
  int wk = tid >> 3;          // 0..31  (w-tile k)
  int wc = (tid & 7) * 16;    // 0..112

  for (int kk = 0; kk < HD; kk += 32) {
    float4 a0 = make_float4(0.f, 0.f, 0.f, 0.f);
    float4 a1 = make_float4(0.f, 0.f, 0.f, 0.f);
    int row = row0 + lr;
    if (row < NN) {
      const float* xp = &X[(size_t)row * HD + kk + lk];
      a0 = *(const float4*)xp;
      a1 = *(const float4*)(xp + 4);
    }
    if constexpr (BN) {
      float4 sc0 = *(const float4*)&scale[kk + lk];
      float4 sc1 = *(const float4*)&scale[kk + lk + 4];
      float4 sh0 = *(const float4*)&shift[kk + lk];
      float4 sh1 = *(const float4*)&shift[kk + lk + 4];
      a0.x = fmaxf(fmaf(sc0.x, a0.x, sh0.x), 0.f);
      a0.y = fmaxf(fmaf(sc0.y, a0.y, sh0.y), 0.f);
      a0.z = fmaxf(fmaf(sc0.z, a0.z, sh0.z), 0.f);
      a0.w = fmaxf(fmaf(sc0.w, a0.w, sh0.w), 0.f);
      a1.x = fmaxf(fmaf(sc1.x, a1.x, sh1.x), 0.f);
      a1.y = fmaxf(fmaf(sc1.y, a1.y, sh1.y), 0.f);
      a1.z = fmaxf(fmaf(sc1.z, a1.z, sh1.z), 0.f);
      a1.w = fmaxf(fmaf(sc1.w, a1.w, sh1.w), 0.f);
    }
    *(float4*)&xt[lr][lk] = a0;
    *(float4*)&xt[lr][lk + 4] = a1;
    const float* wp = &W[(size_t)(kk + wk) * HD + wc];
    *(float4*)&wt[wk][wc]      = *(const float4*)(wp);
    *(float4*)&wt[wk][wc + 4]  = *(const float4*)(wp + 4);
    *(float4*)&wt[wk][wc + 8]  = *(const float4*)(wp + 8);
    *(float4*)&wt[wk][wc + 12] = *(const float4*)(wp + 12);
    __syncthreads();
#pragma unroll 4
    for (int k = 0; k < 32; ++k) {
      float av[4];
#pragma unroll
      for (int i = 0; i < 4; ++i) av[i] = xt[r0 + i][k];
      float2 bv[4];
#pragma unroll
      for (int j = 0; j < 4; ++j) bv[j] = *(const float2*)&wt[k][tc * 2 + 32 * j];
#pragma unroll
      for (int i = 0; i < 4; ++i)
#pragma unroll
        for (int j = 0; j < 4; ++j) {
          acc[i][2 * j]     = fmaf(av[i], bv[j].x, acc[i][2 * j]);
          acc[i][2 * j + 1] = fmaf(av[i], bv[j].y, acc[i][2 * j + 1]);
        }
    }
    __syncthreads();
  }
#pragma unroll
  for (int i = 0; i < 4; ++i) {
    int row = row0 + r0 + i;
    if (row < NN) {
      float dv = dis[row];
#pragma unroll
      for (int j = 0; j < 4; ++j) {
        unsigned p = (f2bf(acc[i][2 * j + 1] * dv) << 16) | f2bf(acc[i][2 * j] * dv);
        HS[(size_t)row * HD2 + tc + 16 * j] = p;
      }
    }
  }
}

// ---------------- aggregation: 4 nodes/wave, 16 lanes/node, uint4/lane ----------------
// One wave-load fetches 4 rows -> gather instr count / 4 (vs 1-node/wave).
// Work-queue (atomic counter) removes static-assignment imbalance.
// MODE 0: AGG[quad] = dis*(sum HS[src] + HS[self]) + b ; accumulate BN stats
// MODE 1: v = relu(same); per-node dot(v, Wl) pooled per graph
template<int MODE>
__global__ __launch_bounds__(256) void k_agg(
    const unsigned* __restrict__ HS, const float* __restrict__ dis,
    const int* __restrict__ rowptr, const int* __restrict__ colidx,
    const float* __restrict__ bias,
    float* __restrict__ AGG, float* __restrict__ stats,
    const int* __restrict__ batch, const float* __restrict__ Wl,
    float* __restrict__ gsum, float* __restrict__ gcnt,
    int* __restrict__ wq) {
  __shared__ float red[16][128];
  int tid = threadIdx.x;
  int lane = tid & 63;
  int il = lane & 15;        // lane within quad
  int q = lane >> 4;         // quad 0..3 (node within group)
  int cbase = il * 8;        // this lane's 8 channels
  float ssum[8], ssq[8];
#pragma unroll
  for (int j = 0; j < 8; ++j) { ssum[j] = 0.f; ssq[j] = 0.f; }
  float bia[8];
  *(float4*)&bia[0] = *(const float4*)&bias[cbase];
  *(float4*)&bia[4] = *(const float4*)&bias[cbase + 4];
  float wl[8];
  if (MODE == 1) {
    *(float4*)&wl[0] = *(const float4*)&Wl[cbase];
    *(float4*)&wl[4] = *(const float4*)&Wl[cbase + 4];
  }
  for (;;) {
    int g = 0;
    if (lane == 0) g = atomicAdd(wq, 1);
    g = __builtin_amdgcn_readfirstlane(g);
    if (g >= NGRP) break;
    int n = g * 4 + q;
    int e0 = rowptr[n], e1 = rowptr[n + 1];
    int deg = e1 - e0;
    int m = deg;                       // wave-wide max degree
    m = max(m, __shfl_xor(m, 16));
    m = max(m, __shfl_xor(m, 32));
    // self row (HS pre-scaled by dis)
    uint4 hs_ = *(const uint4*)&HS[(size_t)n * HD2 + il * 4];
    float acc[8];
    acc[0] = bf_lo(hs_.x); acc[1] = bf_hi(hs_.x);
    acc[2] = bf_lo(hs_.y); acc[3] = bf_hi(hs_.y);
    acc[4] = bf_lo(hs_.z); acc[5] = bf_hi(hs_.z);
    acc[6] = bf_lo(hs_.w); acc[7] = bf_hi(hs_.w);
    int ecl = max(e1 - 1, 0);
    for (int k = 0; k < m; k += 2) {   // 2-deep: 8 lines/wave in flight
      int eA = e0 + k, eB = e0 + k + 1;
      int iA = colidx[min(eA, ecl)];
      int iB = colidx[min(eB, ecl)];
      uint4 hA = *(const uint4*)&HS[(size_t)iA * HD2 + il * 4];
      uint4 hB = *(const uint4*)&HS[(size_t)iB * HD2 + il * 4];
      if (eA >= e1) { hA.x = 0u; hA.y = 0u; hA.z = 0u; hA.w = 0u; }  // bf16 0 -> adds are no-ops
      if (eB >= e1) { hB.x = 0u; hB.y = 0u; hB.z = 0u; hB.w = 0u; }
      acc[0] += bf_lo(hA.x) + bf_lo(hB.x);
      acc[1] += bf_hi(hA.x) + bf_hi(hB.x);
      acc[2] += bf_lo(hA.y) + bf_lo(hB.y);
      acc[3] += bf_hi(hA.y) + bf_hi(hB.y);
      acc[4] += bf_lo(hA.z) + bf_lo(hB.z);
      acc[5] += bf_hi(hA.z) + bf_hi(hB.z);
      acc[6] += bf_lo(hA.w) + bf_lo(hB.w);
      acc[7] += bf_hi(hA.w) + bf_hi(hB.w);
    }
    float di = dis[n];
    if (MODE == 0) {
      float v[8];
#pragma unroll
      for (int j = 0; j < 8; ++j) {
        v[j] = fmaf(di, acc[j], bia[j]);
        ssum[j] += v[j];
        ssq[j] = fmaf(v[j], v[j], ssq[j]);
      }
      *(float4*)&AGG[(size_t)n * HD + cbase]     = make_float4(v[0], v[1], v[2], v[3]);
      *(float4*)&AGG[(size_t)n * HD + cbase + 4] = make_float4(v[4], v[5], v[6], v[7]);
    } else {
      float p = 0.f;
#pragma unroll
      for (int j = 0; j < 8; ++j) {
        float v = fmaxf(fmaf(di, acc[j], bia[j]), 0.f);
        p = fmaf(v, wl[j], p);
      }
      p += __shfl_xor(p, 8);           // width-16 reduce (stays within quad)
      p += __shfl_xor(p, 4);
      p += __shfl_xor(p, 2);
      p += __shfl_xor(p, 1);
      if (il == 0) {
        int b = batch[n];
        atomicAdd(&gsum[b], p);
        atomicAdd(&gcnt[b], 1.0f);
      }
    }
  }
  if (MODE == 0) {
    int r = (tid >> 6) * 4 + q;        // 16 (wave,quad) groups per block
    *(float4*)&red[r][cbase]     = *(float4*)&ssum[0];
    *(float4*)&red[r][cbase + 4] = *(float4*)&ssum[4];
    __syncthreads();
    if (tid < 128) {
      float s = 0.f;
#pragma unroll
      for (int r2 = 0; r2 < 16; ++r2) s += red[r2][tid];
      atomicAdd(&stats[tid], s);
    }
    __syncthreads();
    *(float4*)&red[r][cbase]     = *(float4*)&ssq[0];
    *(float4*)&red[r][cbase + 4] = *(float4*)&ssq[4];
    __syncthreads();
    if (tid < 128) {
      float s = 0.f;
#pragma unroll
      for (int r2 = 0; r2 < 16; ++r2) s += red[r2][tid];
      atomicAdd(&stats[HD + tid], s);
    }
  }
}

// ---------------- BN finalize: per-channel scale/shift ----------------
__global__ void k_bnfin(const float* __restrict__ stats, const float* __restrict__ gamma,
                        const float* __restrict__ beta, float* __restrict__ scale,
                        float* __restrict__ shift) {
  int c = threadIdx.x;
  float inv_n = 1.0f / (float)NN;
  float mean = stats[c] * inv_n;
  float var = stats[HD + c] * inv_n - mean * mean;
  float s = gamma[c] / sqrtf(var + BN_EPS);
  scale[c] = s;
  shift[c] = fmaf(-mean, s, beta[c]);
}

// ---------------- final: mean-pool divide + bias ----------------
__global__ void k_final(const float* __restrict__ gsum, const float* __restrict__ gcnt,
                        const float* __restrict__ bl, float* __restrict__ out) {
  int g = threadIdx.x;
  out[g] = gsum[g] / fmaxf(gcnt[g], 1.0f) + bl[0];
}

extern "C" void kernel_launch(void* const* d_in, const int* in_sizes, int n_in,
                              void* d_out, int out_size, void* d_ws, size_t ws_size,
                              hipStream_t stream) {
  (void)in_sizes; (void)n_in; (void)out_size; (void)ws_size;
  const float* x   = (const float*)d_in[0];
  const int* ei    = (const int*)d_in[1];
  const int* batch = (const int*)d_in[2];
  const float* W1  = (const float*)d_in[3];
  const float* b1  = (const float*)d_in[4];
  const float* g1  = (const float*)d_in[5];
  const float* be1 = (const float*)d_in[6];
  const float* W2  = (const float*)d_in[7];
  const float* b2  = (const float*)d_in[8];
  const float* g2  = (const float*)d_in[9];
  const float* be2 = (const float*)d_in[10];
  const float* W3  = (const float*)d_in[11];
  const float* b3  = (const float*)d_in[12];
  const float* Wl  = (const float*)d_in[13];
  const float* bl  = (const float*)d_in[14];
  float* out = (float*)d_out;

  const int* srcv = ei;        // edge_index[0]
  const int* dstv = ei + NE;   // edge_index[1]

  // ---- workspace layout (all offsets 16B-aligned) ----
  unsigned* hs  = (unsigned*)d_ws;            // [NN][HD2] bf16x2 packed
  float* agg    = (float*)(hs + (size_t)NN * HD2);  // [NN][HD] fp32
  float* dis    = agg + (size_t)NN * HD;      // [NN]
  int*   rowptr = (int*)(dis + NN);           // [NN+1] (padded to NN+4)
  int*   colidx = rowptr + (NN + 4);          // [NE]
  float* scale1 = (float*)(colidx + NE);
  float* shift1 = scale1 + HD;
  float* scale2 = shift1 + HD;
  float* shift2 = scale2 + HD;
  float* zbase  = shift2 + HD;                // ---- zeroed region start ----
  int*   degc   = (int*)zbase;                // [NN]
  int*   fillp  = degc + NN;                  // [NN]
  int*   aux    = fillp + NN;                 // [64]
  int*   auxsc  = aux + 64;                   // [64]
  int*   wq     = auxsc + 64;                 // [4] work-queue counters (3 used)
  float* stats1 = (float*)(wq + 4);           // [256]
  float* stats2 = stats1 + 2 * HD;            // [256]
  float* gsum   = stats2 + 2 * HD;            // [256]
  float* gcnt   = gsum + NGR;                 // [256]
  float* zend   = gcnt + NGR;
  int n4 = (int)(((char*)zend - (char*)zbase) / 16);

  k_zero<<<(n4 + 255) / 256, 256, 0, stream>>>((float4*)zbase, n4);

  // CSR build (once; reused by all 3 layers)
  k_count<<<(NE + 255) / 256, 256, 0, stream>>>(dstv, degc);
  int nchunk = (NN + 1023) / 1024;
  k_scan1<<<nchunk, 1024, 0, stream>>>(degc, rowptr, aux, dis);
  k_scan2<<<1, 1, 0, stream>>>(aux, auxsc, nchunk);
  k_scan3<<<(NN + 255) / 256, 256, 0, stream>>>(rowptr, auxsc);
  k_fill<<<(NE + 255) / 256, 256, 0, stream>>>(srcv, dstv, rowptr, fillp, colidx);

  int gblk = (NN + 63) / 64;
  // layer 1
  k_gemm<false><<<gblk, 256, 0, stream>>>(x, W1, nullptr, nullptr, dis, hs);
  k_agg<0><<<2048, 256, 0, stream>>>(hs, dis, rowptr, colidx, b1, agg, stats1,
                                     nullptr, nullptr, nullptr, nullptr, wq);
  k_bnfin<<<1, HD, 0, stream>>>(stats1, g1, be1, scale1, shift1);
  // layer 2
  k_gemm<true><<<gblk, 256, 0, stream>>>(agg, W2, scale1, shift1, dis, hs);
  k_agg<0><<<2048, 256, 0, stream>>>(hs, dis, rowptr, colidx, b2, agg, stats2,
                                     nullptr, nullptr, nullptr, nullptr, wq + 1);
  k_bnfin<<<1, HD, 0, stream>>>(stats2, g2, be2, scale2, shift2);
  // layer 3 (pool+linear fused)
  k_gemm<true><<<gblk, 256, 0, stream>>>(agg, W3, scale2, shift2, dis, hs);
  k_agg<1><<<2048, 256, 0, stream>>>(hs, dis, rowptr, colidx, b3, nullptr, nullptr,
                                     batch, Wl, gsum, gcnt, wq + 2);
  k_final<<<1, NGR, 0, stream>>>(gsum, gcnt, bl, out);
}

// Round 10
// 698.413 us; speedup vs baseline: 1.5365x; 1.5365x over previous
//
#include <hip/hip_runtime.h>
#include <cstdint>

#define NN 50000
#define NE 600000
#define NGR 256
#define HD 128
#define HD2 64            // bf16x2 packed words per row
#define BN_EPS 1e-5f

typedef __attribute__((ext_vector_type(8))) short bf16x8;
typedef __attribute__((ext_vector_type(4))) float f32x4;

// ---- bf16 pack/unpack (bit ops; values are normal floats, no inf/nan) ----
static __device__ __forceinline__ unsigned f2bf(float f) {
  unsigned u = __float_as_uint(f);
  return (u + 0x7FFFu + ((u >> 16) & 1u)) >> 16;   // round-to-nearest-even
}
static __device__ __forceinline__ float bf_lo(unsigned v) {
  return __uint_as_float(v << 16);
}
static __device__ __forceinline__ float bf_hi(unsigned v) {
  return __uint_as_float(v & 0xFFFF0000u);
}

// ---------------- zero scratch accumulators ----------------
__global__ void k_zero(float4* __restrict__ p, int n4) {
  int i = blockIdx.x * blockDim.x + threadIdx.x;
  if (i < n4) p[i] = make_float4(0.f, 0.f, 0.f, 0.f);
}

// ---------------- in-degree count ----------------
__global__ void k_count(const int* __restrict__ dst, int* __restrict__ cnt) {
  int i = blockIdx.x * blockDim.x + threadIdx.x;
  if (i < NE) atomicAdd(&cnt[dst[i]], 1);
}

// ---------------- CSR row-ptr scan (3 phases) ----------------
__global__ __launch_bounds__(1024) void k_scan1(const int* __restrict__ cnt,
                                                int* __restrict__ rowptr,
                                                int* __restrict__ aux,
                                                float* __restrict__ dis) {
  __shared__ int sd[1024];
  int tid = threadIdx.x;
  int i = blockIdx.x * 1024 + tid;
  int v = (i < NN) ? cnt[i] : 0;
  if (i < NN) dis[i] = 1.0f / sqrtf((float)v + 1.0f);
  sd[tid] = v;
  __syncthreads();
  for (int off = 1; off < 1024; off <<= 1) {
    int t = (tid >= off) ? sd[tid - off] : 0;
    __syncthreads();
    sd[tid] += t;
    __syncthreads();
  }
  if (i < NN) rowptr[i + 1] = sd[tid];
  if (tid == 1023) aux[blockIdx.x] = sd[1023];
}

__global__ void k_scan2(const int* __restrict__ aux, int* __restrict__ auxsc, int nchunks) {
  if (threadIdx.x == 0 && blockIdx.x == 0) {
    int run = 0;
    for (int c = 0; c < nchunks; ++c) { auxsc[c] = run; run += aux[c]; }
  }
}

__global__ void k_scan3(int* __restrict__ rowptr, const int* __restrict__ auxsc) {
  int i = blockIdx.x * blockDim.x + threadIdx.x;
  if (i < NN) rowptr[i + 1] += auxsc[i >> 10];
  if (i == 0) rowptr[0] = 0;
}

__global__ void k_fill(const int* __restrict__ src, const int* __restrict__ dst,
                       const int* __restrict__ rowptr, int* __restrict__ fillp,
                       int* __restrict__ colidx) {
  int i = blockIdx.x * blockDim.x + threadIdx.x;
  if (i < NE) {
    int d = dst[i];
    int p = rowptr[d] + atomicAdd(&fillp[d], 1);
    colidx[p] = src[i];
  }
}

// ---------------- W^T precompute: WT[n][k] = bf16(W[k][n]) ----------------
__global__ void k_wt(const float* __restrict__ W, unsigned short* __restrict__ WT) {
  int idx = blockIdx.x * 256 + threadIdx.x;   // 16384
  int k = idx >> 7, n = idx & 127;
  WT[n * 128 + k] = (unsigned short)f2bf(W[idx]);
}

// ---------------- MFMA GEMM: HS(bf16x2) = dis * (act(X) @ W) ----------------
// Swapped operands: D[n][m] = sum_k WT[n][k] * X[m][k]  (both frags row-contiguous).
// Tile M=64 rows x full N=128 x full K=128. 4 waves; wave w owns m-rows [16w,16w+16).
// LDS chunk-swizzle: 16B chunk c of row r stored at c ^ (r&15)  -> a/b reads 2-way (free).
// act: layer1 = identity (fp32 input); else BN+ReLU on packed-bf16 AGG input.
template<bool BN>
__global__ __launch_bounds__(256) void k_gemm(
    const void* __restrict__ Xv, const unsigned short* __restrict__ WT,
    const float* __restrict__ scale, const float* __restrict__ shift,
    const float* __restrict__ dis, unsigned* __restrict__ HS) {
  __shared__ unsigned short lw[128 * 128];   // WT tile  [n][k]
  __shared__ unsigned short lx[64 * 128];    // X tile   [m][k]
  int tid = threadIdx.x;
  int row0 = blockIdx.x * 64;
  // stage WT -> lw (linear, swizzled)
#pragma unroll
  for (int i = 0; i < 8; ++i) {
    int c2 = tid + 256 * i;                  // 2048 chunks = 128 rows x 16
    int n = c2 >> 4, c = c2 & 15;
    uint4 v = *(const uint4*)&WT[n * 128 + c * 8];
    *(uint4*)&lw[n * 128 + ((c ^ (n & 15)) << 3)] = v;
  }
  // stage X -> lx (convert + optional BN/ReLU, swizzled)
#pragma unroll
  for (int i = 0; i < 4; ++i) {
    int c2 = tid + 256 * i;                  // 1024 chunks = 64 rows x 16
    int m = c2 >> 4, c = c2 & 15;
    int row = row0 + m;
    unsigned short h[8];
    if (row < NN) {
      if constexpr (!BN) {
        const float* X = (const float*)Xv;
        const float* xp = &X[(size_t)row * HD + c * 8];
        float4 a0 = *(const float4*)xp;
        float4 a1 = *(const float4*)(xp + 4);
        h[0] = (unsigned short)f2bf(a0.x); h[1] = (unsigned short)f2bf(a0.y);
        h[2] = (unsigned short)f2bf(a0.z); h[3] = (unsigned short)f2bf(a0.w);
        h[4] = (unsigned short)f2bf(a1.x); h[5] = (unsigned short)f2bf(a1.y);
        h[6] = (unsigned short)f2bf(a1.z); h[7] = (unsigned short)f2bf(a1.w);
      } else {
        const unsigned* X = (const unsigned*)Xv;      // packed bf16 AGG
        uint4 pw = *(const uint4*)&X[(size_t)row * HD2 + c * 4];
        float4 sc0 = *(const float4*)&scale[c * 8];
        float4 sc1 = *(const float4*)&scale[c * 8 + 4];
        float4 sh0 = *(const float4*)&shift[c * 8];
        float4 sh1 = *(const float4*)&shift[c * 8 + 4];
        h[0] = (unsigned short)f2bf(fmaxf(fmaf(sc0.x, bf_lo(pw.x), sh0.x), 0.f));
        h[1] = (unsigned short)f2bf(fmaxf(fmaf(sc0.y, bf_hi(pw.x), sh0.y), 0.f));
        h[2] = (unsigned short)f2bf(fmaxf(fmaf(sc0.z, bf_lo(pw.y), sh0.z), 0.f));
        h[3] = (unsigned short)f2bf(fmaxf(fmaf(sc0.w, bf_hi(pw.y), sh0.w), 0.f));
        h[4] = (unsigned short)f2bf(fmaxf(fmaf(sc1.x, bf_lo(pw.z), sh1.x), 0.f));
        h[5] = (unsigned short)f2bf(fmaxf(fmaf(sc1.y, bf_hi(pw.z), sh1.y), 0.f));
        h[6] = (unsigned short)f2bf(fmaxf(fmaf(sc1.z, bf_lo(pw.w), sh1.z), 0.f));
        h[7] = (unsigned short)f2bf(fmaxf(fmaf(sc1.w, bf_hi(pw.w), sh1.w), 0.f));
      }
    } else {
#pragma unroll
      for (int j = 0; j < 8; ++j) h[j] = 0;
    }
    *(uint4*)&lx[m * 128 + ((c ^ (m & 15)) << 3)] = *(uint4*)h;
  }
  __syncthreads();

  int l = tid & 63, w = tid >> 6;
  int cl = l & 15, g = l >> 4;
  f32x4 acc[8];
#pragma unroll
  for (int nb = 0; nb < 8; ++nb)
#pragma unroll
    for (int z = 0; z < 4; ++z) acc[nb][z] = 0.f;

#pragma unroll
  for (int ks = 0; ks < 4; ++ks) {
    int chunk = ((ks * 4 + g) ^ cl) << 3;    // swizzled 16B chunk byte-half offset (in ushorts)
    bf16x8 b = *(bf16x8*)&lx[(w * 16 + cl) * 128 + chunk];
#pragma unroll
    for (int nb = 0; nb < 8; ++nb) {
      bf16x8 a = *(bf16x8*)&lw[(nb * 16 + cl) * 128 + chunk];
      acc[nb] = __builtin_amdgcn_mfma_f32_16x16x32_bf16(a, b, acc[nb], 0, 0, 0);
    }
  }
  // D[n][m]: lane cl = m-col, row = g*4+j = n. Pack pairs -> HS[m][n/2].
  int m = row0 + w * 16 + cl;
  if (m < NN) {
    float dv = dis[m];
#pragma unroll
    for (int nb = 0; nb < 8; ++nb) {
      unsigned w0 = (f2bf(acc[nb][1] * dv) << 16) | f2bf(acc[nb][0] * dv);
      unsigned w1 = (f2bf(acc[nb][3] * dv) << 16) | f2bf(acc[nb][2] * dv);
      *(uint2*)&HS[(size_t)m * HD2 + nb * 8 + g * 2] = make_uint2(w0, w1);
    }
  }
}

// ---------------- aggregation (CSR gather, bf16x2 rows) — r7 structure ----------------
// MODE 0: v = dis[i]*(sum HS[src] + HS[i]) + b ; write packed bf16 AGG; BN stats (fp32)
// MODE 1: v = relu(same); per-node dot(v, Wl) atomically pooled per graph
template<int MODE>
__global__ __launch_bounds__(256) void k_agg(
    const unsigned* __restrict__ HS, const float* __restrict__ dis,
    const int* __restrict__ rowptr, const int* __restrict__ colidx,
    const float* __restrict__ bias,
    unsigned* __restrict__ AGG, float* __restrict__ stats,
    const int* __restrict__ batch, const float* __restrict__ Wl,
    float* __restrict__ gsum, float* __restrict__ gcnt) {
  __shared__ float red[4][128];
  int tid = threadIdx.x;
  int lane = tid & 63;
  int wv = tid >> 6;        // wave id 0..3, one node per wave per iter
  int c0 = lane * 2;        // this lane's two channels (one packed word)
  float b0 = bias[c0], b1 = bias[c0 + 1];
  float wl0 = 0.f, wl1 = 0.f;
  if (MODE == 1) { wl0 = Wl[c0]; wl1 = Wl[c0 + 1]; }
  float ssum0 = 0.f, ssum1 = 0.f, ssq0 = 0.f, ssq1 = 0.f;
  int stride = gridDim.x * 4;
  for (int i = blockIdx.x * 4 + wv; i < NN; i += stride) {
    unsigned sv = HS[(size_t)i * HD2 + lane];
    float ax = bf_lo(sv), ay = bf_hi(sv);  // self-loop term (HS pre-scaled by dis)
    float bx = 0.f, by = 0.f;              // 4 accumulator chains
    float cx = 0.f, cy = 0.f;
    float dx = 0.f, dy = 0.f;
    int e0 = rowptr[i], e1 = rowptr[i + 1];
    int e = e0;
    for (; e + 7 < e1; e += 8) {
      int s0 = colidx[e];
      int s1 = colidx[e + 1];
      int s2 = colidx[e + 2];
      int s3 = colidx[e + 3];
      int s4 = colidx[e + 4];
      int s5 = colidx[e + 5];
      int s6 = colidx[e + 6];
      int s7 = colidx[e + 7];
      unsigned h0 = HS[(size_t)s0 * HD2 + lane];
      unsigned h1 = HS[(size_t)s1 * HD2 + lane];
      unsigned h2 = HS[(size_t)s2 * HD2 + lane];
      unsigned h3 = HS[(size_t)s3 * HD2 + lane];
      unsigned h4 = HS[(size_t)s4 * HD2 + lane];
      unsigned h5 = HS[(size_t)s5 * HD2 + lane];
      unsigned h6 = HS[(size_t)s6 * HD2 + lane];
      unsigned h7 = HS[(size_t)s7 * HD2 + lane];
      ax += bf_lo(h0); ay += bf_hi(h0);
      bx += bf_lo(h1); by += bf_hi(h1);
      cx += bf_lo(h2); cy += bf_hi(h2);
      dx += bf_lo(h3); dy += bf_hi(h3);
      ax += bf_lo(h4); ay += bf_hi(h4);
      bx += bf_lo(h5); by += bf_hi(h5);
      cx += bf_lo(h6); cy += bf_hi(h6);
      dx += bf_lo(h7); dy += bf_hi(h7);
    }
    for (; e + 3 < e1; e += 4) {
      int s0 = colidx[e];
      int s1 = colidx[e + 1];
      int s2 = colidx[e + 2];
      int s3 = colidx[e + 3];
      unsigned h0 = HS[(size_t)s0 * HD2 + lane];
      unsigned h1 = HS[(size_t)s1 * HD2 + lane];
      unsigned h2 = HS[(size_t)s2 * HD2 + lane];
      unsigned h3 = HS[(size_t)s3 * HD2 + lane];
      ax += bf_lo(h0); ay += bf_hi(h0);
      bx += bf_lo(h1); by += bf_hi(h1);
      cx += bf_lo(h2); cy += bf_hi(h2);
      dx += bf_lo(h3); dy += bf_hi(h3);
    }
    for (; e < e1; ++e) {
      int s0 = colidx[e];
      unsigned h0 = HS[(size_t)s0 * HD2 + lane];
      ax += bf_lo(h0); ay += bf_hi(h0);
    }
    float di = dis[i];
    float vx = fmaf(di, (ax + bx) + (cx + dx), b0);
    float vy = fmaf(di, (ay + by) + (cy + dy), b1);
    if (MODE == 0) {
      AGG[(size_t)i * HD2 + lane] = (f2bf(vy) << 16) | f2bf(vx);
      ssum0 += vx; ssum1 += vy;
      ssq0 = fmaf(vx, vx, ssq0);
      ssq1 = fmaf(vy, vy, ssq1);
    } else {
      vx = fmaxf(vx, 0.f);
      vy = fmaxf(vy, 0.f);
      float p = vx * wl0 + vy * wl1;
#pragma unroll
      for (int m = 32; m >= 1; m >>= 1) p += __shfl_xor(p, m);
      if (lane == 0) {
        int b = batch[i];
        atomicAdd(&gsum[b], p);
        atomicAdd(&gcnt[b], 1.0f);
      }
    }
  }
  if (MODE == 0) {
    red[wv][c0] = ssum0; red[wv][c0 + 1] = ssum1;
    __syncthreads();
    if (wv == 0) {
      float t0 = red[0][c0] + red[1][c0] + red[2][c0] + red[3][c0];
      float t1 = red[0][c0 + 1] + red[1][c0 + 1] + red[2][c0 + 1] + red[3][c0 + 1];
      atomicAdd(&stats[c0], t0);
      atomicAdd(&stats[c0 + 1], t1);
    }
    __syncthreads();
    red[wv][c0] = ssq0; red[wv][c0 + 1] = ssq1;
    __syncthreads();
    if (wv == 0) {
      float q0 = red[0][c0] + red[1][c0] + red[2][c0] + red[3][c0];
      float q1 = red[0][c0 + 1] + red[1][c0 + 1] + red[2][c0 + 1] + red[3][c0 + 1];
      atomicAdd(&stats[HD + c0], q0);
      atomicAdd(&stats[HD + c0 + 1], q1);
    }
  }
}

// ---------------- BN finalize: per-channel scale/shift ----------------
__global__ void k_bnfin(const float* __restrict__ stats, const float* __restrict__ gamma,
                        const float* __restrict__ beta, float* __restrict__ scale,
                        float* __restrict__ shift) {
  int c = threadIdx.x;
  float inv_n = 1.0f / (float)NN;
  float mean = stats[c] * inv_n;
  float var = stats[HD + c] * inv_n - mean * mean;
  float s = gamma[c] / sqrtf(var + BN_EPS);
  scale[c] = s;
  shift[c] = fmaf(-mean, s, beta[c]);
}

// ---------------- final: mean-pool divide + bias ----------------
__global__ void k_final(const float* __restrict__ gsum, const float* __restrict__ gcnt,
                        const float* __restrict__ bl, float* __restrict__ out) {
  int g = threadIdx.x;
  out[g] = gsum[g] / fmaxf(gcnt[g], 1.0f) + bl[0];
}

extern "C" void kernel_launch(void* const* d_in, const int* in_sizes, int n_in,
                              void* d_out, int out_size, void* d_ws, size_t ws_size,
                              hipStream_t stream) {
  (void)in_sizes; (void)n_in; (void)out_size; (void)ws_size;
  const float* x   = (const float*)d_in[0];
  const int* ei    = (const int*)d_in[1];
  const int* batch = (const int*)d_in[2];
  const float* W1  = (const float*)d_in[3];
  const float* b1  = (const float*)d_in[4];
  const float* g1  = (const float*)d_in[5];
  const float* be1 = (const float*)d_in[6];
  const float* W2  = (const float*)d_in[7];
  const float* b2  = (const float*)d_in[8];
  const float* g2  = (const float*)d_in[9];
  const float* be2 = (const float*)d_in[10];
  const float* W3  = (const float*)d_in[11];
  const float* b3  = (const float*)d_in[12];
  const float* Wl  = (const float*)d_in[13];
  const float* bl  = (const float*)d_in[14];
  float* out = (float*)d_out;

  const int* srcv = ei;        // edge_index[0]
  const int* dstv = ei + NE;   // edge_index[1]

  // ---- workspace layout (all offsets 16B-aligned) ----
  unsigned* hs   = (unsigned*)d_ws;                 // [NN][HD2] bf16x2
  unsigned* aggb = hs + (size_t)NN * HD2;           // [NN][HD2] bf16x2
  float* dis     = (float*)(aggb + (size_t)NN * HD2);  // [NN]
  int*   rowptr  = (int*)(dis + NN);                // [NN+1] (padded to NN+4)
  int*   colidx  = rowptr + (NN + 4);               // [NE]
  unsigned short* wtb = (unsigned short*)(colidx + NE);  // [128*128] bf16 W^T
  float* scale1  = (float*)(wtb + 128 * 128);
  float* shift1  = scale1 + HD;
  float* scale2  = shift1 + HD;
  float* shift2  = scale2 + HD;
  float* zbase   = shift2 + HD;                     // ---- zeroed region start ----
  int*   degc    = (int*)zbase;                     // [NN]
  int*   fillp   = degc + NN;                       // [NN]
  int*   aux     = fillp + NN;                      // [64]
  int*   auxsc   = aux + 64;                        // [64]
  float* stats1  = (float*)(auxsc + 64);            // [256]
  float* stats2  = stats1 + 2 * HD;                 // [256]
  float* gsum    = stats2 + 2 * HD;                 // [256]
  float* gcnt    = gsum + NGR;                      // [256]
  float* zend    = gcnt + NGR;
  int n4 = (int)(((char*)zend - (char*)zbase) / 16);

  k_zero<<<(n4 + 255) / 256, 256, 0, stream>>>((float4*)zbase, n4);

  // CSR build (once; reused by all 3 layers)
  k_count<<<(NE + 255) / 256, 256, 0, stream>>>(dstv, degc);
  int nchunk = (NN + 1023) / 1024;
  k_scan1<<<nchunk, 1024, 0, stream>>>(degc, rowptr, aux, dis);
  k_scan2<<<1, 1, 0, stream>>>(aux, auxsc, nchunk);
  k_scan3<<<(NN + 255) / 256, 256, 0, stream>>>(rowptr, auxsc);
  k_fill<<<(NE + 255) / 256, 256, 0, stream>>>(srcv, dstv, rowptr, fillp, colidx);

  int gblk = (NN + 63) / 64;   // 782
  // layer 1
  k_wt<<<64, 256, 0, stream>>>(W1, wtb);
  k_gemm<false><<<gblk, 256, 0, stream>>>(x, wtb, nullptr, nullptr, dis, hs);
  k_agg<0><<<2048, 256, 0, stream>>>(hs, dis, rowptr, colidx, b1, aggb, stats1,
                                     nullptr, nullptr, nullptr, nullptr);
  k_bnfin<<<1, HD, 0, stream>>>(stats1, g1, be1, scale1, shift1);
  // layer 2
  k_wt<<<64, 256, 0, stream>>>(W2, wtb);
  k_gemm<true><<<gblk, 256, 0, stream>>>(aggb, wtb, scale1, shift1, dis, hs);
  k_agg<0><<<2048, 256, 0, stream>>>(hs, dis, rowptr, colidx, b2, aggb, stats2,
                                     nullptr, nullptr, nullptr, nullptr);
  k_bnfin<<<1, HD, 0, stream>>>(stats2, g2, be2, scale2, shift2);
  // layer 3 (BN+ReLU fused into GEMM staging; pool+linear fused into agg)
  k_wt<<<64, 256, 0, stream>>>(W3, wtb);
  k_gemm<true><<<gblk, 256, 0, stream>>>(aggb, wtb, scale2, shift2, dis, hs);
  k_agg<1><<<2048, 256, 0, stream>>>(hs, dis, rowptr, colidx, b3, nullptr, nullptr,
                                     batch, Wl, gsum, gcnt);
  k_final<<<1, NGR, 0, stream>>>(gsum, gcnt, bl, out);
}